// Round 12
// baseline (184.134 us; speedup 1.0000x reference)
//
#include <hip/hip_runtime.h>
#include <stdint.h>

typedef unsigned short u16;
typedef unsigned int u32;
typedef __attribute__((ext_vector_type(8))) short bf16x8;
typedef __attribute__((ext_vector_type(4))) float f32x4;
typedef __attribute__((ext_vector_type(4))) u32 u32x4;

#define DS 2048
#define NROWS 16384
#define MS 1024
#define K2 2048

__device__ __forceinline__ u16 f2bf(float f) {
  u32 u = __float_as_uint(f);
  u32 r = (u + 0x7fffu + ((u >> 16) & 1u)) >> 16;
  return (u16)r;
}

// ---------------- async global->LDS, 16B per lane ----------------
__device__ __forceinline__ void gload16(const u16* g, u16* l) {
  __builtin_amdgcn_global_load_lds(
      (const __attribute__((address_space(1))) void*)g,
      (__attribute__((address_space(3))) void*)l, 16, 0, 0);
}

#define DSR(d, a, IMM) \
  asm volatile("ds_read_b128 %0, %1 offset:%c2" : "=v"(d) : "v"(a), "n"(IMM))
#define CVTPK(d, lo, hi) \
  asm("v_cvt_pk_bf16_f32 %0, %1, %2" : "=v"(d) : "v"(lo), "v"(hi))
#define LGKM(N)                                              \
  asm volatile("s_waitcnt lgkmcnt(" #N ")" ::: "memory");    \
  __builtin_amdgcn_sched_barrier(0)
#define VMW(N) asm volatile("s_waitcnt vmcnt(" #N ")" ::: "memory")
#define SB0() __builtin_amdgcn_sched_barrier(0)
#define PRIO1() __builtin_amdgcn_s_setprio(1)
#define PRIO0() __builtin_amdgcn_s_setprio(0)
#define BAR() __builtin_amdgcn_s_barrier()

// cvt 2x f32x4 -> bf16x8 (element order k0..k7)
#define CVT8(dst, lo, hi)                                         \
  do {                                                            \
    u32 _c0, _c1, _c2, _c3;                                       \
    CVTPK(_c0, lo[0], lo[1]); CVTPK(_c1, lo[2], lo[3]);           \
    CVTPK(_c2, hi[0], hi[1]); CVTPK(_c3, hi[2], hi[3]);           \
    u32x4 _q = {_c0, _c1, _c2, _c3};                              \
    dst = *(bf16x8*)&_q;                                          \
  } while (0)

// ============ mega pre-kernel: split-K V-GEMM + D convert + S->Bt ============
// blocks 0..255    : V = S @ W^T, 512 thr: waves 0-3 K[0,1024), waves 4-7
//                    K[1024,2048); separate LDS dbufs; f32 combine; write Bt odd.
// blocks 256..2303 : D f32 -> Dbf (512 thr x 8 it)
// blocks 2304..2431: S f32 -> Bt even rows
__global__ __launch_bounds__(512) void k_pre(const float* __restrict__ D,
                                             const float* __restrict__ S,
                                             const float* __restrict__ W,
                                             u16* __restrict__ Dbf,
                                             u16* __restrict__ Bt) {
  extern __shared__ float ldsf[];  // 2 groups x 12288 floats (48KB each)
  const int bid = blockIdx.x;
  const int tid = threadIdx.x;

  if (bid >= 256) {
    if (bid < 2304) {  // D convert: 2048 blocks
      size_t i = (size_t)(bid - 256) * 512 + tid;
#pragma unroll
      for (int it = 0; it < 8; ++it, i += (size_t)2048 * 512) {
        float4 v = ((const float4*)D)[i];
        ushort4 o;
        o.x = f2bf(v.x); o.y = f2bf(v.y); o.z = f2bf(v.z); o.w = f2bf(v.w);
        ((ushort4*)Dbf)[i] = o;
      }
    } else {  // S -> Bt even rows: 128 blocks
      size_t j = (size_t)(bid - 2304) * 512 + tid;
#pragma unroll
      for (int it = 0; it < 8; ++it, j += (size_t)128 * 512) {
        float4 v = ((const float4*)S)[j];
        ushort4 o;
        o.x = f2bf(v.x); o.y = f2bf(v.y); o.z = f2bf(v.z); o.w = f2bf(v.w);
        int m = (int)(j >> 9), c4 = (int)(j & 511);
        ((ushort4*)Bt)[(size_t)m * 1024 + c4] = o;
      }
    }
    return;
  }

  // ---- V-GEMM: 64x128 tile, split-K (2 groups of 4 waves, K=1024 each) ----
  const int g = tid >> 8;        // K-half group
  const int gtid = tid & 255;
  const int wid = gtid >> 6, lane = tid & 63;
  const int brow = (bid >> 4) * 64;
  const int bcol = (bid & 15) * 128;
  const int wm = wid >> 1, wn = wid & 1;
  const int l15 = lane & 15, s0 = lane >> 4;

  const int sr = gtid >> 3;
  const int soct = (gtid & 7) ^ (sr & 7);
  const float* gS = S + (size_t)(brow + sr) * 2048 + g * 1024 + soct * 4;
  const float* gW = W + (size_t)(bcol + sr) * 2048 + g * 1024 + soct * 4;

  float* myA = ldsf + g * 12288;           // 2 bufs x 2048 floats
  float* myB = myA + 4096;                 // 2 bufs x 4096 floats
  const u32 lbg = (u32)(uintptr_t)myA;
  const u32 swz = (u32)(((2 * s0) ^ (l15 & 7)) * 16);
  const u32 aA = lbg + (u32)(wm * 32 + l15) * 128 + swz;
  const u32 aAx = aA ^ 16u;
  const u32 aB = lbg + 16384u + (u32)(wn * 64 + l15) * 128 + swz;
  const u32 aBx = aB ^ 16u;

  f32x4 acc[2][4];
#pragma unroll
  for (int i = 0; i < 2; ++i)
#pragma unroll
    for (int j = 0; j < 4; ++j) acc[i][j] = (f32x4){0.f, 0.f, 0.f, 0.f};

#define VSTG(b, kt)                                                               \
  do {                                                                            \
    gload16((const u16*)(gS + (kt)),             (u16*)(myA + (b)*2048 + wid*256)); \
    gload16((const u16*)(gS + 32 * 2048 + (kt)), (u16*)(myA + (b)*2048 + 1024 + wid*256)); \
    gload16((const u16*)(gW + (kt)),             (u16*)(myB + (b)*4096 + wid*256)); \
    gload16((const u16*)(gW + 32 * 2048 + (kt)), (u16*)(myB + (b)*4096 + 1024 + wid*256)); \
    gload16((const u16*)(gW + 64 * 2048 + (kt)), (u16*)(myB + (b)*4096 + 2048 + wid*256)); \
    gload16((const u16*)(gW + 96 * 2048 + (kt)), (u16*)(myB + (b)*4096 + 3072 + wid*256)); \
  } while (0)

  VSTG(0, 0);
#pragma unroll 1
  for (int t = 0; t < 32; ++t) {
    const int b = t & 1;
    const u32 oA = (u32)(b * 8192), oB = (u32)(b * 16384);
    if (t < 31) {
      VSTG(b ^ 1, (t + 1) * 32);
      VMW(6);
    } else {
      VMW(0);
    }
    BAR(); SB0();
    f32x4 qa0, qa1, qa2, qa3;
    f32x4 qb0, qb1, qb2, qb3, qb4, qb5, qb6, qb7;
    DSR(qa0, aA + oA, 0);     DSR(qa1, aAx + oA, 0);
    DSR(qa2, aA + oA, 2048);  DSR(qa3, aAx + oA, 2048);
    DSR(qb0, aB + oB, 0);     DSR(qb1, aBx + oB, 0);
    DSR(qb2, aB + oB, 2048);  DSR(qb3, aBx + oB, 2048);
    DSR(qb4, aB + oB, 4096);  DSR(qb5, aBx + oB, 4096);
    DSR(qb6, aB + oB, 6144);  DSR(qb7, aBx + oB, 6144);
    LGKM(0);
    bf16x8 af[2], bfr[4];
    CVT8(af[0], qa0, qa1); CVT8(af[1], qa2, qa3);
    CVT8(bfr[0], qb0, qb1); CVT8(bfr[1], qb2, qb3);
    CVT8(bfr[2], qb4, qb5); CVT8(bfr[3], qb6, qb7);
    PRIO1();
#pragma unroll
    for (int mi = 0; mi < 2; ++mi)
#pragma unroll
      for (int ni = 0; ni < 4; ++ni)
        acc[mi][ni] = __builtin_amdgcn_mfma_f32_16x16x32_bf16(af[mi], bfr[ni],
                                                              acc[mi][ni], 0, 0, 0);
    PRIO0(); SB0();
    BAR();
  }
#undef VSTG

  // ---- split-K combine via LDS (group1 -> group0), then quantize+write ----
  __syncthreads();
  float* part = ldsf;  // 256 x 36 floats = 36KB (f32x4-aligned, bank-spread)
  if (g == 1) {
#pragma unroll
    for (int mi = 0; mi < 2; ++mi)
#pragma unroll
      for (int ni = 0; ni < 4; ++ni)
        *(f32x4*)&part[gtid * 36 + mi * 16 + ni * 4] = acc[mi][ni];
  }
  __syncthreads();
  if (g == 0) {
    const int crow0 = brow + wm * 32 + s0 * 4;
    const int ccol0 = bcol + wn * 64 + l15;
    u16* C = Bt + 2048;  // odd-row base, stride 4096
#pragma unroll
    for (int mi = 0; mi < 2; ++mi)
#pragma unroll
      for (int ni = 0; ni < 4; ++ni) {
        f32x4 p = *(const f32x4*)&part[gtid * 36 + mi * 16 + ni * 4];
#pragma unroll
        for (int r = 0; r < 4; ++r)
          C[(size_t)(crow0 + mi * 16 + r) * 4096 + (ccol0 + ni * 16)] =
              f2bf(acc[mi][ni][r] + p[r]);
      }
  }
}

// ===== 256^2 GEMM, 4 groups/iter, r12: reads at group START (full-group lead) =
// All 12 ds_reads of a group's data are issued one full group (~2000cy) before
// their LGKM deadline -> steady-state LGKM never stalls. LGKM counts re-derived:
// G_odd {12 carried + 12 new: LGKM(12)->afA+bq0, LGKM(8)->bq1};
// G_even {8 carried + 12 new: LGKM(8)->afB, LGKM(12)=pin}. RD_B0 stays after
// MMAQ(1,0) (WAR on bq0). Stages/VMW(4,4,4,2) identical to r11 (re-audited).
#define SINV 0.022097086912079608f

#define RD_A0(k0, k1, dst)                              \
  DSR(dst[0][0], k0, 0);     DSR(dst[0][1], k1, 0);     \
  DSR(dst[1][0], k0, 2048);  DSR(dst[1][1], k1, 2048);  \
  DSR(dst[2][0], k0, 4096);  DSR(dst[2][1], k1, 4096);  \
  DSR(dst[3][0], k0, 6144);  DSR(dst[3][1], k1, 6144)
#define RD_A1(k0, k1, dst)                              \
  DSR(dst[0][0], k0, 16384); DSR(dst[0][1], k1, 16384); \
  DSR(dst[1][0], k0, 18432); DSR(dst[1][1], k1, 18432); \
  DSR(dst[2][0], k0, 20480); DSR(dst[2][1], k1, 20480); \
  DSR(dst[3][0], k0, 22528); DSR(dst[3][1], k1, 22528)
#define RD_B0(k0, k1, dst)                              \
  DSR(dst[0][0], k0, 0);     DSR(dst[0][1], k1, 0);     \
  DSR(dst[1][0], k0, 2048);  DSR(dst[1][1], k1, 2048)
#define RD_B1(k0, k1, dst)                              \
  DSR(dst[0][0], k0, 16384); DSR(dst[0][1], k1, 16384); \
  DSR(dst[1][0], k0, 18432); DSR(dst[1][1], k1, 18432)

#define MMAQ(AF, BQ, QM, QN)                                                       \
  do {                                                                             \
    _Pragma("unroll") for (int mi = 0; mi < 4; ++mi)                               \
        _Pragma("unroll") for (int ni = 0; ni < 2; ++ni) {                         \
      acc[QM][QN][mi][ni] = __builtin_amdgcn_mfma_f32_16x16x32_bf16(               \
          AF[mi][0], BQ[ni][0], acc[QM][QN][mi][ni], 0, 0, 0);                     \
      acc[QM][QN][mi][ni] = __builtin_amdgcn_mfma_f32_16x16x32_bf16(               \
          AF[mi][1], BQ[ni][1], acc[QM][QN][mi][ni], 0, 0, 0);                     \
    }                                                                              \
  } while (0)

#define STGA(b, h, kt)                                                            \
  do {                                                                            \
    gload16(pA + (size_t)((h) * 128) * K2 + (kt),                                 \
            &lds[(b) * 32768 + (h) * 8192 + wid * 512]);                          \
    gload16(pA + (size_t)((h) * 128 + 64) * K2 + (kt),                            \
            &lds[(b) * 32768 + (h) * 8192 + 4096 + wid * 512]);                   \
  } while (0)
#define STGB(b, h, kt)                                                            \
  do {                                                                            \
    gload16(pB + (size_t)((h) * 128) * K2 + (kt),                                 \
            &lds[(b) * 32768 + 16384 + (h) * 8192 + wid * 512]);                  \
    gload16(pB + (size_t)((h) * 128 + 64) * K2 + (kt),                            \
            &lds[(b) * 32768 + 16384 + (h) * 8192 + 4096 + wid * 512]);           \
  } while (0)

__global__ __launch_bounds__(512, 2) void k_gemm8(const u16* __restrict__ A,
                                                  const u16* __restrict__ Bt,
                                                  float* __restrict__ Pnd) {
  extern __shared__ u16 lds[];
  const int tid = threadIdx.x;
  const int wid = tid >> 6;
  const int lane = tid & 63;
  const int bid = blockIdx.x;
  const int swz = (bid & 7) * 64 + (bid >> 3);
  const int by = swz >> 3, bx = swz & 7;
  const int brow = by * 256, bcol = bx * 256;
  const int wm = wid >> 2, wn = wid & 3;
  const int l15 = lane & 15, s0 = lane >> 4;

  const int tr = tid >> 3;
  const int scol = ((tid & 7) ^ (tr & 7)) << 3;
  const u16* pA = A + (size_t)(brow + tr) * K2 + scol;
  const u16* pB = Bt + (size_t)(bcol + tr) * K2 + scol;

  const u32 lb = (u32)(uintptr_t)(&lds[0]);
  const u32 xorp = ((u32)(s0 ^ (lane & 7))) << 4;
  const u32 aA00 = lb + ((u32)(wm * 64 + l15) << 7) + xorp;
  const u32 aA01 = aA00 ^ 64u;
  const u32 aA10 = aA00 + 65536u;
  const u32 aA11 = aA10 ^ 64u;
  const u32 aB00 = lb + 32768u + ((u32)(wn * 32 + l15) << 7) + xorp;
  const u32 aB01 = aB00 ^ 64u;
  const u32 aB10 = aB00 + 65536u;
  const u32 aB11 = aB10 ^ 64u;

  f32x4 acc[2][2][4][2];
#pragma unroll
  for (int a = 0; a < 2; ++a)
#pragma unroll
    for (int b = 0; b < 2; ++b)
#pragma unroll
      for (int c = 0; c < 4; ++c)
#pragma unroll
        for (int d = 0; d < 2; ++d) acc[a][b][c][d] = (f32x4){0.f, 0.f, 0.f, 0.f};

  bf16x8 afA[4][2], afB[4][2], bq0[2][2], bq1[2][2];

  STGA(0, 0, 0); STGB(0, 0, 0); STGB(0, 1, 0); STGA(0, 1, 0);
  STGA(1, 0, 64);
  VMW(2);
  BAR();
  RD_A0(aA00, aA01, afA);   // 12 outstanding = G1-entry invariant
  RD_B0(aB00, aB01, bq0);

  int kb = 0;
#pragma unroll 1
  for (int j = 0; j < 15; ++j, kb += 128) {
    // G1 (buf0 top): reads at start; LGKM(12)->afA+bq0, LGKM(8)->bq1
    RD_B1(aB00, aB01, bq1);
    RD_A1(aA00, aA01, afB);
    LGKM(12); PRIO1(); MMAQ(afA, bq0, 0, 0); PRIO0();
    STGB(1, 0, kb + 64);
    LGKM(8); PRIO1(); MMAQ(afA, bq1, 0, 1); PRIO0();
    STGB(1, 1, kb + 64);
    STGA(1, 1, kb + 64);
    VMW(4); BAR();
    // G2 (buf0 bottom): RD_A0(buf1) early; RD_B0(buf1) after MMAQ(1,0) (WAR)
    RD_A0(aA10, aA11, afA);
    LGKM(8); PRIO1(); MMAQ(afB, bq0, 1, 0); PRIO0();
    RD_B0(aB10, aB11, bq0);
    STGA(0, 0, kb + 128);
    STGB(0, 0, kb + 128);
    LGKM(12); PRIO1(); MMAQ(afB, bq1, 1, 1); PRIO0();
    VMW(4); BAR();
    // G3 (buf1 top)
    RD_B1(aB10, aB11, bq1);
    RD_A1(aA10, aA11, afB);
    LGKM(12); PRIO1(); MMAQ(afA, bq0, 0, 0); PRIO0();
    STGB(0, 1, kb + 128);
    LGKM(8); PRIO1(); MMAQ(afA, bq1, 0, 1); PRIO0();
    STGA(0, 1, kb + 128);
    VMW(4); BAR();
    // G4 (buf1 bottom)
    RD_A0(aA00, aA01, afA);
    LGKM(8); PRIO1(); MMAQ(afB, bq0, 1, 0); PRIO0();
    RD_B0(aB00, aB01, bq0);
    STGA(1, 0, kb + 192);
    LGKM(12); PRIO1(); MMAQ(afB, bq1, 1, 1); PRIO0();
    VMW(2); BAR();
  }
  // ---- tail: tiles 30 (buf0) + 31 (buf1); kb == 1920 ----
  {
    // T1
    RD_B1(aB00, aB01, bq1);
    RD_A1(aA00, aA01, afB);
    LGKM(12); PRIO1(); MMAQ(afA, bq0, 0, 0); PRIO0();
    STGB(1, 0, kb + 64);
    LGKM(8); PRIO1(); MMAQ(afA, bq1, 0, 1); PRIO0();
    STGB(1, 1, kb + 64);
    STGA(1, 1, kb + 64);
    VMW(4); BAR();
    // T2
    RD_A0(aA10, aA11, afA);
    LGKM(8); PRIO1(); MMAQ(afB, bq0, 1, 0); PRIO0();
    RD_B0(aB10, aB11, bq0);
    LGKM(12); PRIO1(); MMAQ(afB, bq1, 1, 1); PRIO0();
    VMW(0); BAR();
    // T3 (buf1 = tile31)
    RD_B1(aB10, aB11, bq1);
    RD_A1(aA10, aA11, afB);
    LGKM(12); PRIO1(); MMAQ(afA, bq0, 0, 0); PRIO0();
    LGKM(8); PRIO1(); MMAQ(afA, bq1, 0, 1); PRIO0();
    // T4
    LGKM(0); PRIO1(); MMAQ(afB, bq0, 1, 0); MMAQ(afB, bq1, 1, 1); PRIO0();
  }

  // ---------------- fused epilogue ----------------
  __syncthreads();
  float* red = (float*)&lds[0];

#pragma unroll
  for (int qm = 0; qm < 2; ++qm)
#pragma unroll
    for (int mi = 0; mi < 4; ++mi)
#pragma unroll
      for (int r = 0; r < 4; ++r) {
        float num = 0.f, den = 0.f;
#pragma unroll
        for (int qn = 0; qn < 2; ++qn)
#pragma unroll
          for (int ni = 0; ni < 2; ++ni) {
            float v = acc[qm][qn][mi][ni][r];
            float g = __shfl_xor(v, 1);
            float e = __expf(v * SINV);
            num += e * g;
            den += e;
          }
        num += __shfl_xor(num, 2); den += __shfl_xor(den, 2);
        num += __shfl_xor(num, 4); den += __shfl_xor(den, 4);
        num += __shfl_xor(num, 8); den += __shfl_xor(den, 8);
        if (l15 == 0) {
          int slot = qm * 16 + mi * 4 + r;
          red[((wid * 32 + slot) * 4 + s0) * 2 + 0] = num;
          red[((wid * 32 + slot) * 4 + s0) * 2 + 1] = den;
        }
      }
  __syncthreads();
  {
    int rloc = tid >> 1, which = tid & 1;
    int qm = rloc >> 7, wmr = (rloc >> 6) & 1, mi = (rloc >> 4) & 3;
    int lg = (rloc >> 2) & 3, r = rloc & 3;
    int slot = qm * 16 + mi * 4 + r;
    float v = 0.f;
#pragma unroll
    for (int w2 = 0; w2 < 4; ++w2)
      v += red[(((wmr * 4 + w2) * 32 + slot) * 4 + lg) * 2 + which];
    Pnd[((size_t)(brow + rloc) * 8 + bx) * 2 + which] = v;
  }
}

// ---------------- per-row finish ----------------
__global__ __launch_bounds__(256) void k_rowfinal(const float* __restrict__ Pnd,
                                                  float* __restrict__ part) {
  int row = blockIdx.x * 256 + threadIdx.x;
  const float4* p = (const float4*)(Pnd + (size_t)row * 16);
  float num = 0.f, den = 0.f;
#pragma unroll
  for (int i = 0; i < 4; ++i) {
    float4 v = p[i];
    num += v.x + v.z;
    den += v.y + v.w;
  }
  float logit = num / den;
  float ls = (logit >= 0.f) ? -log1pf(__expf(-logit))
                            : (logit - log1pf(__expf(logit)));
  __shared__ float red[4];
#pragma unroll
  for (int off = 32; off > 0; off >>= 1) ls += __shfl_down(ls, off);
  if ((threadIdx.x & 63) == 0) red[threadIdx.x >> 6] = ls;
  __syncthreads();
  if (threadIdx.x == 0) part[blockIdx.x] = red[0] + red[1] + red[2] + red[3];
}

__global__ __launch_bounds__(64) void k_final64(const float* __restrict__ part,
                                                float* __restrict__ out) {
  float v = part[threadIdx.x];
#pragma unroll
  for (int off = 32; off > 0; off >>= 1) v += __shfl_down(v, off);
  if (threadIdx.x == 0) out[0] = v;
}

extern "C" void kernel_launch(void* const* d_in, const int* in_sizes, int n_in,
                              void* d_out, int out_size, void* d_ws, size_t ws_size,
                              hipStream_t stream) {
  const float* D = (const float*)d_in[0];
  const float* S = (const float*)d_in[1];
  const float* W = (const float*)d_in[2];

  char* w = (char*)d_ws;
  u16* Dbf = (u16*)w; w += (size_t)NROWS * DS * 2;       // 67 MB
  u16* Bt = (u16*)w;  w += (size_t)DS * DS * 2;          // 8 MB (interleaved S/V)
  float* Pnd = (float*)w; w += (size_t)NROWS * 16 * 4;   // 1 MB
  float* part = (float*)w;                               // 256 B

  (void)hipFuncSetAttribute((const void*)k_gemm8,
                            hipFuncAttributeMaxDynamicSharedMemorySize, 131072);
  (void)hipFuncSetAttribute((const void*)k_pre,
                            hipFuncAttributeMaxDynamicSharedMemorySize, 98304);

  k_pre<<<2432, 512, 98304, stream>>>(D, S, W, Dbf, Bt);
  k_gemm8<<<512, 512, 131072, stream>>>(Dbf, Bt, Pnd);
  k_rowfinal<<<NROWS / 256, 256, 0, stream>>>(Pnd, part);
  k_final64<<<1, 64, 0, stream>>>(part, (float*)d_out);
}

// Round 13
// 167.101 us; speedup vs baseline: 1.1019x; 1.1019x over previous
//
#include <hip/hip_runtime.h>
#include <stdint.h>

typedef unsigned short u16;
typedef unsigned int u32;
typedef __attribute__((ext_vector_type(8))) short bf16x8;
typedef __attribute__((ext_vector_type(4))) float f32x4;
typedef __attribute__((ext_vector_type(4))) u32 u32x4;

#define DS 2048
#define NROWS 16384
#define MS 1024
#define K2 2048

__device__ __forceinline__ u16 f2bf(float f) {
  u32 u = __float_as_uint(f);
  u32 r = (u + 0x7fffu + ((u >> 16) & 1u)) >> 16;
  return (u16)r;
}

// ---------------- async global->LDS, 16B per lane ----------------
__device__ __forceinline__ void gload16(const u16* g, u16* l) {
  __builtin_amdgcn_global_load_lds(
      (const __attribute__((address_space(1))) void*)g,
      (__attribute__((address_space(3))) void*)l, 16, 0, 0);
}

#define DSR(d, a, IMM) \
  asm volatile("ds_read_b128 %0, %1 offset:%c2" : "=v"(d) : "v"(a), "n"(IMM))
#define CVTPK(d, lo, hi) \
  asm("v_cvt_pk_bf16_f32 %0, %1, %2" : "=v"(d) : "v"(lo), "v"(hi))
#define LGKM(N)                                              \
  asm volatile("s_waitcnt lgkmcnt(" #N ")" ::: "memory");    \
  __builtin_amdgcn_sched_barrier(0)
#define VMW(N) asm volatile("s_waitcnt vmcnt(" #N ")" ::: "memory")
#define SB0() __builtin_amdgcn_sched_barrier(0)
#define PRIO1() __builtin_amdgcn_s_setprio(1)
#define PRIO0() __builtin_amdgcn_s_setprio(0)
#define BAR() __builtin_amdgcn_s_barrier()

// cvt 2x f32x4 -> bf16x8 (element order k0..k7)
#define CVT8(dst, lo, hi)                                         \
  do {                                                            \
    u32 _c0, _c1, _c2, _c3;                                       \
    CVTPK(_c0, lo[0], lo[1]); CVTPK(_c1, lo[2], lo[3]);           \
    CVTPK(_c2, hi[0], hi[1]); CVTPK(_c3, hi[2], hi[3]);           \
    u32x4 _q = {_c0, _c1, _c2, _c3};                              \
    dst = *(bf16x8*)&_q;                                          \
  } while (0)

// ============ mega pre-kernel: V-GEMM(f32 in) + D convert + S->Bt ============
// (r11 version — static 48KB LDS so convert blocks keep high occupancy)
__global__ __launch_bounds__(256) void k_pre(const float* __restrict__ D,
                                             const float* __restrict__ S,
                                             const float* __restrict__ W,
                                             u16* __restrict__ Dbf,
                                             u16* __restrict__ Bt) {
  __shared__ float lsA[2][64 * 32];
  __shared__ float lsB[2][128 * 32];
  const int bid = blockIdx.x;
  const int tid = threadIdx.x;

  if (bid >= 256) {
    if (bid < 2304) {  // D convert
      size_t i = (size_t)(bid - 256) * 256 + tid;
#pragma unroll
      for (int it = 0; it < 16; ++it, i += (size_t)2048 * 256) {
        float4 v = ((const float4*)D)[i];
        ushort4 o;
        o.x = f2bf(v.x); o.y = f2bf(v.y); o.z = f2bf(v.z); o.w = f2bf(v.w);
        ((ushort4*)Dbf)[i] = o;
      }
    } else {  // S -> Bt even rows
      size_t j = (size_t)(bid - 2304) * 256 + tid;
#pragma unroll
      for (int it = 0; it < 16; ++it, j += (size_t)128 * 256) {
        float4 v = ((const float4*)S)[j];
        ushort4 o;
        o.x = f2bf(v.x); o.y = f2bf(v.y); o.z = f2bf(v.z); o.w = f2bf(v.w);
        int m = (int)(j >> 9), c4 = (int)(j & 511);
        ((ushort4*)Bt)[(size_t)m * 1024 + c4] = o;
      }
    }
    return;
  }

  // ---- V-GEMM: 64x128 tile, K=2048, f32 staged to LDS, cvt at fragment ----
  const int wid = tid >> 6, lane = tid & 63;
  const int brow = (bid >> 4) * 64;
  const int bcol = (bid & 15) * 128;
  const int wm = wid >> 1, wn = wid & 1;
  const int l15 = lane & 15, s0 = lane >> 4;

  const int sr = tid >> 3;
  const int soct = (tid & 7) ^ (sr & 7);
  const float* gS = S + (size_t)(brow + sr) * 2048 + soct * 4;
  const float* gW = W + (size_t)(bcol + sr) * 2048 + soct * 4;

  const u32 lbA = (u32)(uintptr_t)&lsA[0][0];
  const u32 lbB = (u32)(uintptr_t)&lsB[0][0];
  const u32 swz = (u32)(((2 * s0) ^ (l15 & 7)) * 16);
  const u32 aA = lbA + (u32)(wm * 32 + l15) * 128 + swz;
  const u32 aAx = aA ^ 16u;
  const u32 aB = lbB + (u32)(wn * 64 + l15) * 128 + swz;
  const u32 aBx = aB ^ 16u;

  f32x4 acc[2][4];
#pragma unroll
  for (int i = 0; i < 2; ++i)
#pragma unroll
    for (int j = 0; j < 4; ++j) acc[i][j] = (f32x4){0.f, 0.f, 0.f, 0.f};

#define VSTG(b, kt)                                                              \
  do {                                                                           \
    gload16((const u16*)(gS + (kt)),             (u16*)(&lsA[b][0] + wid * 256)); \
    gload16((const u16*)(gS + 32 * 2048 + (kt)), (u16*)(&lsA[b][1024] + wid * 256)); \
    gload16((const u16*)(gW + (kt)),             (u16*)(&lsB[b][0] + wid * 256)); \
    gload16((const u16*)(gW + 32 * 2048 + (kt)), (u16*)(&lsB[b][1024] + wid * 256)); \
    gload16((const u16*)(gW + 64 * 2048 + (kt)), (u16*)(&lsB[b][2048] + wid * 256)); \
    gload16((const u16*)(gW + 96 * 2048 + (kt)), (u16*)(&lsB[b][3072] + wid * 256)); \
  } while (0)

  VSTG(0, 0);
#pragma unroll 1
  for (int t = 0; t < 64; ++t) {
    const int b = t & 1;
    const u32 oA = (u32)(b * 8192), oB = (u32)(b * 16384);
    if (t < 63) {
      VSTG(b ^ 1, (t + 1) * 32);
      VMW(6);
    } else {
      VMW(0);
    }
    BAR(); SB0();
    f32x4 qa0, qa1, qa2, qa3;
    f32x4 qb0, qb1, qb2, qb3, qb4, qb5, qb6, qb7;
    DSR(qa0, aA + oA, 0);     DSR(qa1, aAx + oA, 0);
    DSR(qa2, aA + oA, 2048);  DSR(qa3, aAx + oA, 2048);
    DSR(qb0, aB + oB, 0);     DSR(qb1, aBx + oB, 0);
    DSR(qb2, aB + oB, 2048);  DSR(qb3, aBx + oB, 2048);
    DSR(qb4, aB + oB, 4096);  DSR(qb5, aBx + oB, 4096);
    DSR(qb6, aB + oB, 6144);  DSR(qb7, aBx + oB, 6144);
    LGKM(0);
    bf16x8 af[2], bfr[4];
    CVT8(af[0], qa0, qa1); CVT8(af[1], qa2, qa3);
    CVT8(bfr[0], qb0, qb1); CVT8(bfr[1], qb2, qb3);
    CVT8(bfr[2], qb4, qb5); CVT8(bfr[3], qb6, qb7);
    PRIO1();
#pragma unroll
    for (int mi = 0; mi < 2; ++mi)
#pragma unroll
      for (int ni = 0; ni < 4; ++ni)
        acc[mi][ni] = __builtin_amdgcn_mfma_f32_16x16x32_bf16(af[mi], bfr[ni],
                                                              acc[mi][ni], 0, 0, 0);
    PRIO0(); SB0();
    BAR();
  }
#undef VSTG

  const int crow0 = brow + wm * 32 + s0 * 4;
  const int ccol0 = bcol + wn * 64 + l15;
  u16* C = Bt + 2048;
#pragma unroll
  for (int mi = 0; mi < 2; ++mi)
#pragma unroll
    for (int ni = 0; ni < 4; ++ni)
#pragma unroll
      for (int r = 0; r < 4; ++r)
        C[(size_t)(crow0 + mi * 16 + r) * 4096 + (ccol0 + ni * 16)] =
            f2bf(acc[mi][ni][r]);
}

// ===== 256^2 GEMM, 4 groups/iter (r11 schedule — best measured) ==============
#define SINV 0.022097086912079608f

#define RD_A0(k0, k1, dst)                              \
  DSR(dst[0][0], k0, 0);     DSR(dst[0][1], k1, 0);     \
  DSR(dst[1][0], k0, 2048);  DSR(dst[1][1], k1, 2048);  \
  DSR(dst[2][0], k0, 4096);  DSR(dst[2][1], k1, 4096);  \
  DSR(dst[3][0], k0, 6144);  DSR(dst[3][1], k1, 6144)
#define RD_A1(k0, k1, dst)                              \
  DSR(dst[0][0], k0, 16384); DSR(dst[0][1], k1, 16384); \
  DSR(dst[1][0], k0, 18432); DSR(dst[1][1], k1, 18432); \
  DSR(dst[2][0], k0, 20480); DSR(dst[2][1], k1, 20480); \
  DSR(dst[3][0], k0, 22528); DSR(dst[3][1], k1, 22528)
#define RD_B0(k0, k1, dst)                              \
  DSR(dst[0][0], k0, 0);     DSR(dst[0][1], k1, 0);     \
  DSR(dst[1][0], k0, 2048);  DSR(dst[1][1], k1, 2048)
#define RD_B1(k0, k1, dst)                              \
  DSR(dst[0][0], k0, 16384); DSR(dst[0][1], k1, 16384); \
  DSR(dst[1][0], k0, 18432); DSR(dst[1][1], k1, 18432)

#define MMAQ(AF, BQ, QM, QN)                                                       \
  do {                                                                             \
    _Pragma("unroll") for (int mi = 0; mi < 4; ++mi)                               \
        _Pragma("unroll") for (int ni = 0; ni < 2; ++ni) {                         \
      acc[QM][QN][mi][ni] = __builtin_amdgcn_mfma_f32_16x16x32_bf16(               \
          AF[mi][0], BQ[ni][0], acc[QM][QN][mi][ni], 0, 0, 0);                     \
      acc[QM][QN][mi][ni] = __builtin_amdgcn_mfma_f32_16x16x32_bf16(               \
          AF[mi][1], BQ[ni][1], acc[QM][QN][mi][ni], 0, 0, 0);                     \
    }                                                                              \
  } while (0)

#define STGA(b, h, kt)                                                            \
  do {                                                                            \
    gload16(pA + (size_t)((h) * 128) * K2 + (kt),                                 \
            &lds[(b) * 32768 + (h) * 8192 + wid * 512]);                          \
    gload16(pA + (size_t)((h) * 128 + 64) * K2 + (kt),                            \
            &lds[(b) * 32768 + (h) * 8192 + 4096 + wid * 512]);                   \
  } while (0)
#define STGB(b, h, kt)                                                            \
  do {                                                                            \
    gload16(pB + (size_t)((h) * 128) * K2 + (kt),                                 \
            &lds[(b) * 32768 + 16384 + (h) * 8192 + wid * 512]);                  \
    gload16(pB + (size_t)((h) * 128 + 64) * K2 + (kt),                            \
            &lds[(b) * 32768 + 16384 + (h) * 8192 + 4096 + wid * 512]);           \
  } while (0)

__global__ __launch_bounds__(512, 2) void k_gemm8(const u16* __restrict__ A,
                                                  const u16* __restrict__ Bt,
                                                  float* __restrict__ Pnd) {
  extern __shared__ u16 lds[];
  const int tid = threadIdx.x;
  const int wid = tid >> 6;
  const int lane = tid & 63;
  const int bid = blockIdx.x;
  const int swz = (bid & 7) * 64 + (bid >> 3);
  const int by = swz >> 3, bx = swz & 7;
  const int brow = by * 256, bcol = bx * 256;
  const int wm = wid >> 2, wn = wid & 3;
  const int l15 = lane & 15, s0 = lane >> 4;

  const int tr = tid >> 3;
  const int scol = ((tid & 7) ^ (tr & 7)) << 3;
  const u16* pA = A + (size_t)(brow + tr) * K2 + scol;
  const u16* pB = Bt + (size_t)(bcol + tr) * K2 + scol;

  const u32 lb = (u32)(uintptr_t)(&lds[0]);
  const u32 xorp = ((u32)(s0 ^ (lane & 7))) << 4;
  const u32 aA00 = lb + ((u32)(wm * 64 + l15) << 7) + xorp;
  const u32 aA01 = aA00 ^ 64u;
  const u32 aA10 = aA00 + 65536u;
  const u32 aA11 = aA10 ^ 64u;
  const u32 aB00 = lb + 32768u + ((u32)(wn * 32 + l15) << 7) + xorp;
  const u32 aB01 = aB00 ^ 64u;
  const u32 aB10 = aB00 + 65536u;
  const u32 aB11 = aB10 ^ 64u;

  f32x4 acc[2][2][4][2];
#pragma unroll
  for (int a = 0; a < 2; ++a)
#pragma unroll
    for (int b = 0; b < 2; ++b)
#pragma unroll
      for (int c = 0; c < 4; ++c)
#pragma unroll
        for (int d = 0; d < 2; ++d) acc[a][b][c][d] = (f32x4){0.f, 0.f, 0.f, 0.f};

  bf16x8 afA[4][2], afB[4][2], bq0[2][2], bq1[2][2];

  STGA(0, 0, 0); STGB(0, 0, 0); STGB(0, 1, 0); STGA(0, 1, 0);
  STGA(1, 0, 64);
  VMW(2);
  BAR();
  RD_A0(aA00, aA01, afA);
  RD_B0(aB00, aB01, bq0);

  int kb = 0;
#pragma unroll 1
  for (int j = 0; j < 15; ++j, kb += 128) {
    // G1: consume buf0 top; stage buf1.Bh0, buf1.Bh1, buf1.Ah1
    STGB(1, 0, kb + 64);
    RD_B1(aB00, aB01, bq1);
    LGKM(4); PRIO1(); MMAQ(afA, bq0, 0, 0); PRIO0();
    STGB(1, 1, kb + 64);
    STGA(1, 1, kb + 64);
    RD_A1(aA00, aA01, afB);
    LGKM(8); PRIO1(); MMAQ(afA, bq1, 0, 1); PRIO0(); VMW(4); BAR();
    // G2: consume buf0 bottom; stage buf0'.Ah0, buf0'.Bh0; read buf1 h0 set
    LGKM(0); PRIO1(); MMAQ(afB, bq0, 1, 0); PRIO0();
    STGA(0, 0, kb + 128);
    STGB(0, 0, kb + 128);
    RD_A0(aA10, aA11, afA);
    RD_B0(aB10, aB11, bq0);
    LGKM(12); PRIO1(); MMAQ(afB, bq1, 1, 1); PRIO0(); VMW(4); BAR();
    // G3: consume buf1 top; stage buf0'.Bh1, buf0'.Ah1
    STGB(0, 1, kb + 128);
    RD_B1(aB10, aB11, bq1);
    LGKM(4); PRIO1(); MMAQ(afA, bq0, 0, 0); PRIO0();
    STGA(0, 1, kb + 128);
    RD_A1(aA10, aA11, afB);
    LGKM(8); PRIO1(); MMAQ(afA, bq1, 0, 1); PRIO0(); VMW(4); BAR();
    // G4: consume buf1 bottom; stage buf1'.Ah0; read next buf0 h0 set
    LGKM(0); PRIO1(); MMAQ(afB, bq0, 1, 0); PRIO0();
    STGA(1, 0, kb + 192);
    RD_A0(aA00, aA01, afA);
    RD_B0(aB00, aB01, bq0);
    LGKM(12); PRIO1(); MMAQ(afB, bq1, 1, 1); PRIO0(); VMW(2); BAR();
  }
  // ---- tail: tiles 30 (buf0) + 31 (buf1); kb == 1920 ----
  {
    STGB(1, 0, kb + 64);
    RD_B1(aB00, aB01, bq1);
    LGKM(4); PRIO1(); MMAQ(afA, bq0, 0, 0); PRIO0();
    STGB(1, 1, kb + 64);
    STGA(1, 1, kb + 64);
    RD_A1(aA00, aA01, afB);
    LGKM(8); PRIO1(); MMAQ(afA, bq1, 0, 1); PRIO0(); VMW(4); BAR();
    LGKM(0); PRIO1(); MMAQ(afB, bq0, 1, 0); PRIO0();
    RD_A0(aA10, aA11, afA);
    RD_B0(aB10, aB11, bq0);
    LGKM(12); PRIO1(); MMAQ(afB, bq1, 1, 1); PRIO0(); VMW(0); BAR();
    RD_B1(aB10, aB11, bq1);
    LGKM(4); PRIO1(); MMAQ(afA, bq0, 0, 0); PRIO0();
    RD_A1(aA10, aA11, afB);
    LGKM(8); PRIO1(); MMAQ(afA, bq1, 0, 1); PRIO0();
    LGKM(0); PRIO1(); MMAQ(afB, bq0, 1, 0); MMAQ(afB, bq1, 1, 1); PRIO0();
  }

  // ---------------- fused epilogue ----------------
  __syncthreads();
  float* red = (float*)&lds[0];

#pragma unroll
  for (int qm = 0; qm < 2; ++qm)
#pragma unroll
    for (int mi = 0; mi < 4; ++mi)
#pragma unroll
      for (int r = 0; r < 4; ++r) {
        float num = 0.f, den = 0.f;
#pragma unroll
        for (int qn = 0; qn < 2; ++qn)
#pragma unroll
          for (int ni = 0; ni < 2; ++ni) {
            float v = acc[qm][qn][mi][ni][r];
            float g = __shfl_xor(v, 1);
            float e = __expf(v * SINV);
            num += e * g;
            den += e;
          }
        num += __shfl_xor(num, 2); den += __shfl_xor(den, 2);
        num += __shfl_xor(num, 4); den += __shfl_xor(den, 4);
        num += __shfl_xor(num, 8); den += __shfl_xor(den, 8);
        if (l15 == 0) {
          int slot = qm * 16 + mi * 4 + r;
          red[((wid * 32 + slot) * 4 + s0) * 2 + 0] = num;
          red[((wid * 32 + slot) * 4 + s0) * 2 + 1] = den;
        }
      }
  __syncthreads();
  {
    int rloc = tid >> 1, which = tid & 1;
    int qm = rloc >> 7, wmr = (rloc >> 6) & 1, mi = (rloc >> 4) & 3;
    int lg = (rloc >> 2) & 3, r = rloc & 3;
    int slot = qm * 16 + mi * 4 + r;
    float v = 0.f;
#pragma unroll
    for (int w2 = 0; w2 < 4; ++w2)
      v += red[(((wmr * 4 + w2) * 32 + slot) * 4 + lg) * 2 + which];
    Pnd[((size_t)(brow + rloc) * 8 + bx) * 2 + which] = v;
  }
}

// ---------------- per-row finish ----------------
__global__ __launch_bounds__(256) void k_rowfinal(const float* __restrict__ Pnd,
                                                  float* __restrict__ part) {
  int row = blockIdx.x * 256 + threadIdx.x;
  const float4* p = (const float4*)(Pnd + (size_t)row * 16);
  float num = 0.f, den = 0.f;
#pragma unroll
  for (int i = 0; i < 4; ++i) {
    float4 v = p[i];
    num += v.x + v.z;
    den += v.y + v.w;
  }
  float logit = num / den;
  float ls = (logit >= 0.f) ? -log1pf(__expf(-logit))
                            : (logit - log1pf(__expf(logit)));
  __shared__ float red[4];
#pragma unroll
  for (int off = 32; off > 0; off >>= 1) ls += __shfl_down(ls, off);
  if ((threadIdx.x & 63) == 0) red[threadIdx.x >> 6] = ls;
  __syncthreads();
  if (threadIdx.x == 0) part[blockIdx.x] = red[0] + red[1] + red[2] + red[3];
}

__global__ __launch_bounds__(64) void k_final64(const float* __restrict__ part,
                                                float* __restrict__ out) {
  float v = part[threadIdx.x];
#pragma unroll
  for (int off = 32; off > 0; off >>= 1) v += __shfl_down(v, off);
  if (threadIdx.x == 0) out[0] = v;
}

extern "C" void kernel_launch(void* const* d_in, const int* in_sizes, int n_in,
                              void* d_out, int out_size, void* d_ws, size_t ws_size,
                              hipStream_t stream) {
  const float* D = (const float*)d_in[0];
  const float* S = (const float*)d_in[1];
  const float* W = (const float*)d_in[2];

  char* w = (char*)d_ws;
  u16* Dbf = (u16*)w; w += (size_t)NROWS * DS * 2;       // 67 MB
  u16* Bt = (u16*)w;  w += (size_t)DS * DS * 2;          // 8 MB (interleaved S/V)
  float* Pnd = (float*)w; w += (size_t)NROWS * 16 * 4;   // 1 MB
  float* part = (float*)w;                               // 256 B

  (void)hipFuncSetAttribute((const void*)k_gemm8,
                            hipFuncAttributeMaxDynamicSharedMemorySize, 131072);

  k_pre<<<2432, 256, 0, stream>>>(D, S, W, Dbf, Bt);
  k_gemm8<<<512, 512, 131072, stream>>>(Dbf, Bt, Pnd);
  k_rowfinal<<<NROWS / 256, 256, 0, stream>>>(Pnd, part);
  k_final64<<<1, 64, 0, stream>>>(part, (float*)d_out);
}